// Round 7
// baseline (282.545 us; speedup 1.0000x reference)
//
#include <hip/hip_runtime.h>
#include <hip/hip_bf16.h>
#include <hip/hip_fp16.h>

#define N_NODES 50000
#define N_EDGES 800000
#define C_H 128
#define C_OUT 64
#define NBLK 196          // ceil(50000/256)
#define TSTRIDE 136       // LDS tile row stride in bf16
#define E_PAD 950272      // >= N_EDGES + 3*N_NODES, 1024-aligned
#define MM_BLKS 782       // ceil(50000/64) row-tiles for 16-row-tile matmuls
#define SLAB 800000       // shorts per 16-channel slab: 50000*16 (1.6 MB, L2-resident)

typedef __attribute__((ext_vector_type(8))) short bf16x8;
typedef __attribute__((ext_vector_type(4))) float f32x4;

static __device__ __forceinline__ float bf_lo(unsigned int u) { return __uint_as_float(u << 16); }
static __device__ __forceinline__ float bf_hi(unsigned int u) { return __uint_as_float(u & 0xffff0000u); }
static __device__ __forceinline__ unsigned short f2bf(float f) {
    __hip_bfloat16 h = __float2bfloat16(f);
    return *(unsigned short*)&h;
}
static __device__ __forceinline__ unsigned int pack2(float a, float b) {
    return (unsigned int)f2bf(a) | ((unsigned int)f2bf(b) << 16);
}
static __device__ __forceinline__ unsigned short f2h_bits(float f) {
    union { __half h; unsigned short u; } c; c.h = __float2half_rn(f); return c.u;
}
static __device__ __forceinline__ float h_bits2f(unsigned short u) {
    union { __half h; unsigned short u; } c; c.u = u; return __half2float(c.h);
}

// ================= prep: hist(+rank) + pack W + zero epay =================
// block ranges: [0,3125) hist | [3125,3413) pack | [3413,4341) zero
__global__ void prep_kernel(const int* __restrict__ dst, int* __restrict__ counts,
                            int* __restrict__ rank,
                            const float* __restrict__ W1, const float* __restrict__ W2,
                            const float* __restrict__ W3, const float* __restrict__ Wd1,
                            const float* __restrict__ Wd2,
                            unsigned short* __restrict__ P1, unsigned short* __restrict__ P2,
                            unsigned short* __restrict__ P3, unsigned short* __restrict__ Pd1,
                            unsigned short* __restrict__ Pd2,
                            unsigned int* __restrict__ epay) {
    int b = blockIdx.x;
    if (b < 3125) {                               // hist over edges, capture rank
        int e = b * 256 + threadIdx.x;
        rank[e] = atomicAdd(&counts[dst[e]], 1);
    } else if (b < 3413) {                        // pack weights
        int idx = (b - 3125) * 256 + threadIdx.x;
        if (idx < 4 * 16384) {
            int which = idx >> 14;
            int r = idx & 16383;
            const float* W = (which == 0) ? W1 : (which == 1) ? W2 : (which == 2) ? W3 : Wd1;
            unsigned short* P = (which == 0) ? P1 : (which == 1) ? P2 : (which == 2) ? P3 : Pd1;
            int j = r & 7, lane = (r >> 3) & 63, t = r >> 9;
            int nb = t & 7, kb = t >> 3;          // NB=8
            int k = kb * 32 + ((lane >> 4) << 3) + j;
            int n = nb * 16 + (lane & 15);
            P[r] = f2bf(W[(size_t)k * 128 + n]);
        } else {
            int r = idx - 65536;
            if (r < 8192) {
                int j = r & 7, lane = (r >> 3) & 63, t = r >> 9;
                int nb = t & 3, kb = t >> 2;      // NB=4
                int k = kb * 32 + ((lane >> 4) << 3) + j;
                int n = nb * 16 + (lane & 15);
                Pd2[r] = f2bf(Wd2[(size_t)k * 64 + n]);
            }
        }
    } else {                                      // zero epay: 928 blocks x 1024 uints
        int i = (b - 3413) * 256 + threadIdx.x;
        *(uint4*)(epay + (size_t)i * 4) = make_uint4(0, 0, 0, 0);
    }
}

// ================= CSR scans (degree padded to multiple of 4) =================
__global__ void __launch_bounds__(256) scan1_kernel(const int* __restrict__ counts,
                                                    int* __restrict__ eblk,
                                                    int* __restrict__ bsum,
                                                    float* __restrict__ dinv) {
    __shared__ int ws[4];
    int i = blockIdx.x * 256 + threadIdx.x;
    int v = (i < N_NODES) ? counts[i] : 0;
    if (i < N_NODES) dinv[i] = rsqrtf((float)v + 1.0f);
    int vp = (v + 3) & ~3;                        // padded degree
    int lane = threadIdx.x & 63, w = threadIdx.x >> 6;
    int x = vp;
    #pragma unroll
    for (int off = 1; off < 64; off <<= 1) {
        int t = __shfl_up(x, off, 64);
        if (lane >= off) x += t;
    }
    if (lane == 63) ws[w] = x;
    __syncthreads();
    if (threadIdx.x == 0) {
        int run = 0;
        #pragma unroll
        for (int k = 0; k < 4; ++k) { int t = ws[k]; ws[k] = run; run += t; }
        bsum[blockIdx.x] = run;
    }
    __syncthreads();
    if (i < N_NODES) eblk[i] = x - vp + ws[w];
}

// merged scan2+scan3
__global__ void __launch_bounds__(256) scanB_kernel(const int* __restrict__ eblk,
                                                    const int* __restrict__ bsum,
                                                    int* __restrict__ rowptr) {
    __shared__ int ws[4];
    __shared__ int sbo;
    int i = threadIdx.x;
    int v = (i < NBLK) ? bsum[i] : 0;
    int lane = i & 63, w = i >> 6;
    int x = v;
    #pragma unroll
    for (int off = 1; off < 64; off <<= 1) {
        int t = __shfl_up(x, off, 64);
        if (lane >= off) x += t;
    }
    if (lane == 63) ws[w] = x;
    __syncthreads();
    if (i == 0) {
        int run = 0;
        #pragma unroll
        for (int k = 0; k < 4; ++k) { int t = ws[k]; ws[k] = run; run += t; }
    }
    __syncthreads();
    int excl = x - v + ws[w];
    if (i == (int)blockIdx.x) sbo = excl;
    if (blockIdx.x == 0 && i == NBLK - 1) rowptr[N_NODES] = excl + v;
    __syncthreads();
    int g = blockIdx.x * 256 + threadIdx.x;
    if (g < N_NODES) rowptr[g] = eblk[g] + sbo;
}

// ================= heterogeneous: XW1 matmul (slab-major out) + csr fill ==========
__global__ void __launch_bounds__(256) fill_mm_kernel(
        const float* __restrict__ x, const unsigned short* __restrict__ P1,
        unsigned short* __restrict__ XW1,
        const int* __restrict__ src, const int* __restrict__ dst,
        const float* __restrict__ dinv,
        const int* __restrict__ rowptr, const int* __restrict__ rank,
        unsigned int* __restrict__ epay) {
    int b = blockIdx.x;
    if (b < MM_BLKS) {
        const int lane = threadIdx.x & 63;
        const int wave = threadIdx.x >> 6;
        const int wid  = b * 4 + wave;
        if (wid * 16 >= N_NODES) return;          // exact: 3125 waves used
        const int node = wid * 16 + (lane & 15);
        const int quad = lane >> 4;
        f32x4 acc[8];
        #pragma unroll
        for (int nb = 0; nb < 8; ++nb) acc[nb] = (f32x4){0.f, 0.f, 0.f, 0.f};
        #pragma unroll
        for (int kb = 0; kb < 4; ++kb) {
            const float* p = x + (size_t)node * 128 + kb * 32 + quad * 8;
            float4 lo = *(const float4*)p;
            float4 hi = *(const float4*)(p + 4);
            union { bf16x8 v; unsigned int u[4]; } tmp;
            tmp.u[0] = pack2(lo.x, lo.y); tmp.u[1] = pack2(lo.z, lo.w);
            tmp.u[2] = pack2(hi.x, hi.y); tmp.u[3] = pack2(hi.z, hi.w);
            #pragma unroll
            for (int nb = 0; nb < 8; ++nb) {
                bf16x8 wf = *(const bf16x8*)(P1 + ((size_t)(kb * 8 + nb) * 64 + lane) * 8);
                acc[nb] = __builtin_amdgcn_mfma_f32_16x16x32_bf16(wf, tmp.v, acc[nb], 0, 0, 0);
            }
        }
        #pragma unroll
        for (int nb = 0; nb < 8; ++nb) {          // slab nb, offset quad*4
            uint2 o;
            o.x = pack2(acc[nb][0], acc[nb][1]);
            o.y = pack2(acc[nb][2], acc[nb][3]);
            *(uint2*)(XW1 + (size_t)nb * SLAB + (size_t)node * 16 + quad * 4) = o;
        }
    } else {
        int e = (b - MM_BLKS) * 256 + threadIdx.x;
        if (e < N_EDGES) {
            int d = dst[e], s = src[e];
            int pos = rowptr[d] + rank[e];
            float nrm = dinv[s] * dinv[d];
            epay[pos] = (unsigned int)s | ((unsigned int)f2h_bits(nrm) << 16);
        }
    }
}

// ================= XCD-sliced aggregation over slab-major features ===============
// slice = blockIdx & 7 -> all slice-s blocks on XCD s (round-robin dispatch).
// Slice s reads ONLY slab s: contiguous 50000*32 B = 1.6 MB < 4 MB per-XCD L2,
// fully line-resident, every fetched 128 B line fully consumed.
// 2 threads/node x 8 slices = 16 chains/node (same as fused baseline).
template <bool BIASRELU>
__global__ void __launch_bounds__(256) agg_kernel(
        const int* __restrict__ rowptr,
        const unsigned int* __restrict__ epay,
        const float* __restrict__ dinv,
        const unsigned short* __restrict__ hin,   // slab-major [8][N][16]
        const float* __restrict__ bias,
        unsigned short* __restrict__ out) {       // slab-major [8][N][16]
    const int t = threadIdx.x;
    const unsigned int b = blockIdx.x;
    const int slice = (int)(b & 7u);
    const int node  = (int)(b >> 3) * 128 + (t >> 1);
    if (node >= N_NODES) return;
    const int half = t & 1;                       // which 8-ch half of the slab
    const unsigned short* hslab = hin + (size_t)slice * SLAB + half * 8;

    float di = dinv[node], dii = di * di;
    uint4 raw = *(const uint4*)(hslab + (size_t)node * 16);
    float a0 = bf_lo(raw.x) * dii, a1 = bf_hi(raw.x) * dii;
    float a2 = bf_lo(raw.y) * dii, a3 = bf_hi(raw.y) * dii;
    float a4 = bf_lo(raw.z) * dii, a5 = bf_hi(raw.z) * dii;
    float a6 = bf_lo(raw.w) * dii, a7 = bf_hi(raw.w) * dii;

    int beg = rowptr[node], end = rowptr[node + 1];
    int p = beg;
    for (; p + 8 <= end; p += 8) {
        uint4 ev0 = *(const uint4*)(epay + p);
        uint4 ev1 = *(const uint4*)(epay + p + 4);
        unsigned int ee[8] = {ev0.x, ev0.y, ev0.z, ev0.w, ev1.x, ev1.y, ev1.z, ev1.w};
        uint4 rv[8];
        #pragma unroll
        for (int j = 0; j < 8; ++j)
            rv[j] = *(const uint4*)(hslab + (size_t)(ee[j] & 0xffffu) * 16);
        #pragma unroll
        for (int j = 0; j < 8; ++j) {
            float nm = h_bits2f((unsigned short)(ee[j] >> 16));
            a0 = fmaf(bf_lo(rv[j].x), nm, a0); a1 = fmaf(bf_hi(rv[j].x), nm, a1);
            a2 = fmaf(bf_lo(rv[j].y), nm, a2); a3 = fmaf(bf_hi(rv[j].y), nm, a3);
            a4 = fmaf(bf_lo(rv[j].z), nm, a4); a5 = fmaf(bf_hi(rv[j].z), nm, a5);
            a6 = fmaf(bf_lo(rv[j].w), nm, a6); a7 = fmaf(bf_hi(rv[j].w), nm, a7);
        }
    }
    if (p < end) {
        uint4 ev = *(const uint4*)(epay + p);
        unsigned int ee[4] = {ev.x, ev.y, ev.z, ev.w};
        uint4 rv[4];
        #pragma unroll
        for (int j = 0; j < 4; ++j)
            rv[j] = *(const uint4*)(hslab + (size_t)(ee[j] & 0xffffu) * 16);
        #pragma unroll
        for (int j = 0; j < 4; ++j) {
            float nm = h_bits2f((unsigned short)(ee[j] >> 16));
            a0 = fmaf(bf_lo(rv[j].x), nm, a0); a1 = fmaf(bf_hi(rv[j].x), nm, a1);
            a2 = fmaf(bf_lo(rv[j].y), nm, a2); a3 = fmaf(bf_hi(rv[j].y), nm, a3);
            a4 = fmaf(bf_lo(rv[j].z), nm, a4); a5 = fmaf(bf_hi(rv[j].z), nm, a5);
            a6 = fmaf(bf_lo(rv[j].w), nm, a6); a7 = fmaf(bf_hi(rv[j].w), nm, a7);
        }
    }
    if (BIASRELU) {
        int c8 = slice * 16 + half * 8;
        float4 ba = *(const float4*)(bias + c8);
        float4 bb = *(const float4*)(bias + c8 + 4);
        a0 = fmaxf(a0 + ba.x, 0.f); a1 = fmaxf(a1 + ba.y, 0.f);
        a2 = fmaxf(a2 + ba.z, 0.f); a3 = fmaxf(a3 + ba.w, 0.f);
        a4 = fmaxf(a4 + bb.x, 0.f); a5 = fmaxf(a5 + bb.y, 0.f);
        a6 = fmaxf(a6 + bb.z, 0.f); a7 = fmaxf(a7 + bb.w, 0.f);
    }
    uint4 o;
    o.x = pack2(a0, a1); o.y = pack2(a2, a3);
    o.z = pack2(a4, a5); o.w = pack2(a6, a7);
    *(uint4*)(out + (size_t)slice * SLAB + (size_t)node * 16 + half * 8) = o;
}

// ========= dense mm: out = relu(hin @ Wp + bias), slab-major in/out =========
__global__ void __launch_bounds__(256) mmbr_kernel(
        const unsigned short* __restrict__ hin,
        const unsigned short* __restrict__ Wp,
        const float* __restrict__ bias,
        unsigned short* __restrict__ out) {
    const int lane = threadIdx.x & 63;
    const int wave = threadIdx.x >> 6;
    const int wid  = blockIdx.x * 4 + wave;
    if (wid * 16 >= N_NODES) return;              // exact: 3125 waves used
    const int node = wid * 16 + (lane & 15);
    const int quad = lane >> 4;
    f32x4 acc[8];
    #pragma unroll
    for (int nb = 0; nb < 8; ++nb) acc[nb] = (f32x4){0.f, 0.f, 0.f, 0.f};
    #pragma unroll
    for (int kb = 0; kb < 4; ++kb) {
        int slab = kb * 2 + (quad >> 1);
        int off  = (quad & 1) * 8;
        bf16x8 hf = *(const bf16x8*)(hin + (size_t)slab * SLAB + (size_t)node * 16 + off);
        #pragma unroll
        for (int nb = 0; nb < 8; ++nb) {
            bf16x8 wf = *(const bf16x8*)(Wp + ((size_t)(kb * 8 + nb) * 64 + lane) * 8);
            acc[nb] = __builtin_amdgcn_mfma_f32_16x16x32_bf16(wf, hf, acc[nb], 0, 0, 0);
        }
    }
    #pragma unroll
    for (int nb = 0; nb < 8; ++nb) {
        int ch = nb * 16 + quad * 4;
        float4 bb = *(const float4*)(bias + ch);
        uint2 o;
        o.x = pack2(fmaxf(acc[nb][0] + bb.x, 0.f), fmaxf(acc[nb][1] + bb.y, 0.f));
        o.y = pack2(fmaxf(acc[nb][2] + bb.z, 0.f), fmaxf(acc[nb][3] + bb.w, 0.f));
        *(uint2*)(out + (size_t)nb * SLAB + (size_t)node * 16 + quad * 4) = o;
    }
}

// ======== final: relu(G3@W3+b3) -> relu(@Wd1+bd1) -> @Wd2+bd2 -> sigmoid ========
__global__ void __launch_bounds__(256) final_kernel(
        const unsigned short* __restrict__ g3,    // slab-major
        const unsigned short* __restrict__ P3p, const float* __restrict__ b3,
        const unsigned short* __restrict__ Wd1p, const float* __restrict__ bd1,
        const unsigned short* __restrict__ Wd2p, const float* __restrict__ bd2,
        float* __restrict__ out_f) {
    __shared__ unsigned short sG[16 * TSTRIDE];
    const int t = threadIdx.x;
    {
        int nl = t >> 4, c8 = (t & 15) << 3;
        int node = blockIdx.x * 16 + nl;
        uint4 v = *(const uint4*)(g3 + (size_t)(c8 >> 4) * SLAB + (size_t)node * 16 + (c8 & 15));
        *(uint4*)(sG + nl * TSTRIDE + c8) = v;
    }
    __syncthreads();

    const int lane = t & 63, wave = t >> 6, quad = lane >> 4, row = lane & 15;
    const int node = blockIdx.x * 16 + row;
    const int nb0 = 2 * wave, nb1 = 2 * wave + 1;

    // stage 1: @P3 + b3, relu
    f32x4 acc0 = (f32x4){0.f, 0.f, 0.f, 0.f};
    f32x4 acc1 = (f32x4){0.f, 0.f, 0.f, 0.f};
    #pragma unroll
    for (int kb = 0; kb < 4; ++kb) {
        bf16x8 hf = *(const bf16x8*)(sG + row * TSTRIDE + kb * 32 + quad * 8);
        bf16x8 wf0 = *(const bf16x8*)(P3p + ((size_t)(kb * 8 + nb0) * 64 + lane) * 8);
        bf16x8 wf1 = *(const bf16x8*)(P3p + ((size_t)(kb * 8 + nb1) * 64 + lane) * 8);
        acc0 = __builtin_amdgcn_mfma_f32_16x16x32_bf16(wf0, hf, acc0, 0, 0, 0);
        acc1 = __builtin_amdgcn_mfma_f32_16x16x32_bf16(wf1, hf, acc1, 0, 0, 0);
    }
    float4 ba0 = *(const float4*)(b3 + nb0 * 16 + quad * 4);
    float4 ba1 = *(const float4*)(b3 + nb1 * 16 + quad * 4);
    float v00 = fmaxf(acc0[0] + ba0.x, 0.f), v01 = fmaxf(acc0[1] + ba0.y, 0.f);
    float v02 = fmaxf(acc0[2] + ba0.z, 0.f), v03 = fmaxf(acc0[3] + ba0.w, 0.f);
    float v10 = fmaxf(acc1[0] + ba1.x, 0.f), v11 = fmaxf(acc1[1] + ba1.y, 0.f);
    float v12 = fmaxf(acc1[2] + ba1.z, 0.f), v13 = fmaxf(acc1[3] + ba1.w, 0.f);
    __syncthreads();
    {
        uint2 o0, o1;
        o0.x = pack2(v00, v01); o0.y = pack2(v02, v03);
        o1.x = pack2(v10, v11); o1.y = pack2(v12, v13);
        *(uint2*)(sG + row * TSTRIDE + nb0 * 16 + quad * 4) = o0;
        *(uint2*)(sG + row * TSTRIDE + nb1 * 16 + quad * 4) = o1;
    }
    __syncthreads();

    // stage 2: @Wd1 + bd1, relu
    acc0 = (f32x4){0.f, 0.f, 0.f, 0.f};
    acc1 = (f32x4){0.f, 0.f, 0.f, 0.f};
    #pragma unroll
    for (int kb = 0; kb < 4; ++kb) {
        bf16x8 hf = *(const bf16x8*)(sG + row * TSTRIDE + kb * 32 + quad * 8);
        bf16x8 wf0 = *(const bf16x8*)(Wd1p + ((size_t)(kb * 8 + nb0) * 64 + lane) * 8);
        bf16x8 wf1 = *(const bf16x8*)(Wd1p + ((size_t)(kb * 8 + nb1) * 64 + lane) * 8);
        acc0 = __builtin_amdgcn_mfma_f32_16x16x32_bf16(wf0, hf, acc0, 0, 0, 0);
        acc1 = __builtin_amdgcn_mfma_f32_16x16x32_bf16(wf1, hf, acc1, 0, 0, 0);
    }
    ba0 = *(const float4*)(bd1 + nb0 * 16 + quad * 4);
    ba1 = *(const float4*)(bd1 + nb1 * 16 + quad * 4);
    v00 = fmaxf(acc0[0] + ba0.x, 0.f); v01 = fmaxf(acc0[1] + ba0.y, 0.f);
    v02 = fmaxf(acc0[2] + ba0.z, 0.f); v03 = fmaxf(acc0[3] + ba0.w, 0.f);
    v10 = fmaxf(acc1[0] + ba1.x, 0.f); v11 = fmaxf(acc1[1] + ba1.y, 0.f);
    v12 = fmaxf(acc1[2] + ba1.z, 0.f); v13 = fmaxf(acc1[3] + ba1.w, 0.f);
    __syncthreads();
    {
        uint2 o0, o1;
        o0.x = pack2(v00, v01); o0.y = pack2(v02, v03);
        o1.x = pack2(v10, v11); o1.y = pack2(v12, v13);
        *(uint2*)(sG + row * TSTRIDE + nb0 * 16 + quad * 4) = o0;
        *(uint2*)(sG + row * TSTRIDE + nb1 * 16 + quad * 4) = o1;
    }
    __syncthreads();

    // stage 3: @Wd2 + bd2 -> sigmoid
    f32x4 acc = (f32x4){0.f, 0.f, 0.f, 0.f};
    #pragma unroll
    for (int kb = 0; kb < 4; ++kb) {
        bf16x8 hf = *(const bf16x8*)(sG + row * TSTRIDE + kb * 32 + quad * 8);
        bf16x8 wf = *(const bf16x8*)(Wd2p + ((size_t)(kb * 4 + wave) * 64 + lane) * 8);
        acc = __builtin_amdgcn_mfma_f32_16x16x32_bf16(wf, hf, acc, 0, 0, 0);
    }
    int ch = wave * 16 + quad * 4;
    float4 b4 = *(const float4*)(bd2 + ch);
    float4 rr;
    rr.x = 1.f / (1.f + expf(-(acc[0] + b4.x)));
    rr.y = 1.f / (1.f + expf(-(acc[1] + b4.y)));
    rr.z = 1.f / (1.f + expf(-(acc[2] + b4.z)));
    rr.w = 1.f / (1.f + expf(-(acc[3] + b4.w)));
    *(float4*)(out_f + (size_t)node * C_OUT + ch) = rr;
}

extern "C" void kernel_launch(void* const* d_in, const int* in_sizes, int n_in,
                              void* d_out, int out_size, void* d_ws, size_t ws_size,
                              hipStream_t stream) {
    const float* x   = (const float*)d_in[0];
    const int*   ei  = (const int*)d_in[1];
    const float* W1  = (const float*)d_in[2];
    const float* b1  = (const float*)d_in[3];
    const float* W2  = (const float*)d_in[4];
    const float* b2  = (const float*)d_in[5];
    const float* W3  = (const float*)d_in[6];
    const float* b3  = (const float*)d_in[7];
    const float* Wd1 = (const float*)d_in[8];
    const float* bd1 = (const float*)d_in[9];
    const float* Wd2 = (const float*)d_in[10];
    const float* bd2 = (const float*)d_in[11];

    const int* src = ei;
    const int* dst = ei + N_EDGES;

    char* base = (char*)d_ws;
    size_t off = 0;
    auto alloc = [&](size_t bytes) { char* p = base + off; off += (bytes + 255) & ~size_t(255); return p; };
    int*            counts = (int*)alloc(50176 * 4);
    unsigned int*   epay   = (unsigned int*)alloc((size_t)E_PAD * 4);
    int*            rank   = (int*)alloc((size_t)N_EDGES * 4);
    float*          dinv   = (float*)alloc(N_NODES * 4);
    int*            rowptr = (int*)alloc((N_NODES + 1) * 4);
    int*            eblk   = (int*)alloc(N_NODES * 4);
    int*            bsum   = (int*)alloc(256 * 4);
    unsigned short* XW1    = (unsigned short*)alloc((size_t)8 * SLAB * 2);
    unsigned short* bufA   = (unsigned short*)alloc((size_t)8 * SLAB * 2);
    unsigned short* bufB   = (unsigned short*)alloc((size_t)8 * SLAB * 2);
    unsigned short* P1     = (unsigned short*)alloc(128 * 128 * 2);
    unsigned short* P2     = (unsigned short*)alloc(128 * 128 * 2);
    unsigned short* P3     = (unsigned short*)alloc(128 * 128 * 2);
    unsigned short* Pd1    = (unsigned short*)alloc(128 * 128 * 2);
    unsigned short* Pd2    = (unsigned short*)alloc(128 * 64 * 2);

    const int T = 256;
    dim3 blk(T);
    dim3 gN((N_NODES + T - 1) / T);            // 196
    dim3 gPrep(3125 + 288 + 928);              // hist + pack + zero
    dim3 gFillMM(MM_BLKS + 3125);              // mm + fill
    dim3 gAgg(391 * 8);                        // slice = blockIdx & 7 -> per-XCD slab
    dim3 gMM(MM_BLKS);                         // 782
    dim3 gFinal(N_NODES / 16);                 // 3125, exact

    hipMemsetAsync(counts, 0, 50176 * 4, stream);
    prep_kernel<<<gPrep, blk, 0, stream>>>(dst, counts, rank,
                                           W1, W2, W3, Wd1, Wd2,
                                           P1, P2, P3, Pd1, Pd2, epay);
    scan1_kernel<<<gN, blk, 0, stream>>>(counts, eblk, bsum, dinv);
    scanB_kernel<<<gN, blk, 0, stream>>>(eblk, bsum, rowptr);
    fill_mm_kernel<<<gFillMM, blk, 0, stream>>>(x, P1, XW1, src, dst, dinv,
                                                rowptr, rank, epay);

    // layer 1: A1 = relu(agg(x@W1) + b1)            XW1 -> bufA
    agg_kernel<true><<<gAgg, blk, 0, stream>>>(rowptr, epay, dinv, XW1, b1, bufA);
    // layer 2: G2 = agg(A1)                         bufA -> bufB
    agg_kernel<false><<<gAgg, blk, 0, stream>>>(rowptr, epay, dinv, bufA, nullptr, bufB);
    //          A2 = relu(G2@W2 + b2)                bufB -> XW1
    mmbr_kernel<<<gMM, blk, 0, stream>>>(bufB, P2, b2, XW1);
    // layer 3: G3 = agg(A2)                         XW1 -> bufB
    agg_kernel<false><<<gAgg, blk, 0, stream>>>(rowptr, epay, dinv, XW1, nullptr, bufB);
    // head: relu(G3@W3+b3) -> relu(@Wd1+bd1) -> @Wd2+bd2 -> sigmoid
    final_kernel<<<gFinal, blk, 0, stream>>>(bufB, P3, b3, Pd1, bd1, Pd2, bd2,
                                             (float*)d_out);
}